// Round 11
// baseline (241.845 us; speedup 1.0000x reference)
//
#include <hip/hip_runtime.h>
#include <cstdint>
#include <cstddef>

#define SEQ   2048
#define EDIM  256
#define FFND  512
#define NBATCH 16
#define XLD   264   // xt row pitch (u16): 528B/row == 4-dword bank rotation

typedef unsigned short u16;
typedef __attribute__((ext_vector_type(8))) __bf16 bf16x8;
typedef __attribute__((ext_vector_type(4))) float f32x4;

__device__ __forceinline__ float bf2f(u16 u) {
  union { unsigned int w; float f; } v; v.w = ((unsigned int)u) << 16; return v.f;
}
__device__ __forceinline__ u16 f2bf(float f) {
  union { float f; unsigned int w; } v; v.f = f;
  unsigned int r = v.w + 0x7fffu + ((v.w >> 16) & 1u);
  return (u16)(r >> 16);
}
__device__ __forceinline__ float fast_cos(float x) {
  float r = x * 0.15915494309189535f;
  r = r - floorf(r);
  return __builtin_amdgcn_cosf(r);
}
__device__ __forceinline__ void unpack8(bf16x8 v, float* o) {
  const u16* p = (const u16*)&v;
  #pragma unroll
  for (int j = 0; j < 8; ++j) o[j] = bf2f(p[j]);
}
// self-sniff: 512B of embed; f32 data -> ~half "exponent" fields > 128; bf16 -> ~none.
__device__ __forceinline__ int sniff128(const void* embed) {
  const unsigned* p = (const unsigned*)embed;
  int c = 0;
  #pragma unroll
  for (int j = 0; j < 128; ++j) {
    unsigned v = p[j];
    c += (((v >> 7) & 0xffu) > 128u) ? 1 : 0;
    c += (((v >> 23) & 0xffu) > 128u) ? 1 : 0;
  }
  return c > 32;
}
__device__ __forceinline__ float cvt(const void* p, int j, int isf32) {
  return isf32 ? ((const float*)p)[j] : bf2f(((const u16*)p)[j]);
}

struct CanonArgs { const void* p[14]; };

// ---- prep_all: canonical bf16 params + cwT/l2T staging layout + w1f/b1f f32 ----
// transpose loops indexed for CONTIGUOUS READS (writes scatter; L2 absorbs)
__global__ void prep_kernel(const void* __restrict__ emb, CanonArgs a,
                            u16* __restrict__ canon, u16* __restrict__ cwT,
                            u16* __restrict__ l2T, float* __restrict__ w1f,
                            float* __restrict__ b1f) {
  const int isf32 = sniff128(emb);
  int id = blockIdx.x * 256 + threadIdx.x;
  if (id < 406162) {
    const int off[15] = {0, 128, 131200, 131712, 131728, 139920, 140944, 403088,
                         403600, 404112, 404624, 405136, 405648, 406160, 406162};
    int s = 0;
    #pragma unroll
    for (int k = 0; k < 13; ++k) s += (id >= off[k + 1]) ? 1 : 0;
    canon[id] = f2bf(cvt(a.p[s], id - off[s], isf32));
  } else if (id < 537234) {
    int j = id - 406162;                    // (l,k,n), n fastest -> read contiguous
    int l = j >> 16, k = (j >> 8) & 255, n = j & 255;
    u16 v = f2bf(cvt(a.p[1], l * 65536 + k * 256 + n, isf32));
    cwT[l * 65536 + (k >> 3) * 2048 + n * 8 + (k & 7)] = v;
  } else if (id < 799378) {
    int j = id - 537234;
    int l = j >> 17, k = (j >> 8) & 511, n = j & 255;
    u16 v = f2bf(cvt(a.p[6], l * 131072 + k * 256 + n, isf32));
    l2T[l * 131072 + (k >> 3) * 2048 + n * 8 + (k & 7)] = v;
  } else if (id < 807570) {
    int j = id - 799378;                    // [2][8][512] plain f32
    w1f[j] = cvt(a.p[4], j, isf32);
  } else if (id < 808594) {
    int j = id - 807570;                    // [2][512] f32
    b1f[j] = cvt(a.p[5], j, isf32);
  }
}

// ====== MEGA (M=32 tiles, 1024 blocks, 4 blocks/CU) ======
// embed+PE -> [attn GEMM+LN1 -> q(regs) -> ffn GEMM+LN2] x2 -> pool, all in LDS
__launch_bounds__(256, 4)
__global__ void mega_kernel(const int* __restrict__ tokens, const void* __restrict__ embed,
                            const u16* __restrict__ canon, const u16* __restrict__ cwT,
                            const u16* __restrict__ l2T, const float* __restrict__ w1f,
                            const float* __restrict__ b1f, float* __restrict__ pooled) {
  __shared__ u16 xt[32 * XLD];          // 16896 B persistent x tile
  __shared__ union {
    struct { u16 Bt[4 * 256 * 8]; u16 At[4 * 32 * 8]; } k;   // 16384 + 2048
    struct { float2 part[32][17]; float2 ms[32]; } ln;       // 4352 + 256
  } sh;

  const int tid = threadIdx.x;
  const int wave = tid >> 6, lane = tid & 63;
  const int fr = lane & 15, fq = lane >> 4;
  const int m0 = blockIdx.x * 32;
  const int isf32 = sniff128(embed);
  const int sr_ = tid & 31, sg = tid >> 5;   // staging row / col-group (4 cols)

  int cols[4];
  #pragma unroll
  for (int ni = 0; ni < 4; ++ni) cols[ni] = wave * 64 + ni * 16 + fr;

  // ---------- embed + inline PE -> xt ----------
  {
    const float c0 = 9.210340371976184f / 128.f;   // ln(10000)/128
    const float inv2pi = 0.15915494309189535f;
    #pragma unroll
    for (int it = 0; it < 4; ++it) {
      int c = it * 256 + tid;
      int r = c >> 5, e8 = c & 31;
      int tok = tokens[m0 + r];
      float ev[8];
      if (isf32) {
        const float* ep = (const float*)embed + (size_t)tok * EDIM + e8 * 8;
        float4 a = *(const float4*)ep, b = *(const float4*)(ep + 4);
        ev[0]=a.x; ev[1]=a.y; ev[2]=a.z; ev[3]=a.w; ev[4]=b.x; ev[5]=b.y; ev[6]=b.z; ev[7]=b.w;
      } else {
        const u16* ep = (const u16*)embed + (size_t)tok * EDIM + e8 * 8;
        uint4 v = *(const uint4*)ep;
        unpack8(*(const bf16x8*)&v, ev);
      }
      int s = (m0 + r) & (SEQ - 1);
      u16 o[8];
      #pragma unroll
      for (int j = 0; j < 8; ++j) {
        int e = e8 * 8 + j, i = e >> 1;
        float rev = (float)s * (__expf(-(float)i * c0) * inv2pi);
        rev = rev - floorf(rev);
        float pe = (e & 1) ? __builtin_amdgcn_cosf(rev) : __builtin_amdgcn_sinf(rev);
        o[j] = f2bf(ev[j] + pe);
      }
      *(uint4*)(xt + r * XLD + e8 * 8) = *(const uint4*)o;
    }
  }
  __syncthreads();

  f32x4 acc[2][4];

  auto mfma_step = [&]() {
    const bf16x8* Av = (const bf16x8*)sh.k.At;
    const bf16x8* Bv = (const bf16x8*)sh.k.Bt;
    bf16x8 af[2], bfv[4];
    #pragma unroll
    for (int mi = 0; mi < 2; ++mi) af[mi] = Av[fq * 32 + ((mi * 16 + fr) ^ fq)];
    #pragma unroll
    for (int ni = 0; ni < 4; ++ni) bfv[ni] = Bv[fq * 256 + cols[ni]];
    #pragma unroll
    for (int mi = 0; mi < 2; ++mi)
      #pragma unroll
      for (int ni = 0; ni < 4; ++ni)
        acc[mi][ni] = __builtin_amdgcn_mfma_f32_16x16x32_bf16(af[mi], bfv[ni], acc[mi][ni], 0, 0, 0);
  };

  // bias + residual + LN; xt updated in place
  auto epilogue = [&](const u16* bias, const u16* gamma, const u16* beta) {
    float bcol[4];
    #pragma unroll
    for (int ni = 0; ni < 4; ++ni) bcol[ni] = bf2f(bias[cols[ni]]);
    #pragma unroll
    for (int mi = 0; mi < 2; ++mi)
      #pragma unroll
      for (int rg = 0; rg < 4; ++rg) {
        int lrow = mi * 16 + fq * 4 + rg;
        float a = 0.f, b = 0.f;
        #pragma unroll
        for (int ni = 0; ni < 4; ++ni) {
          float t2 = acc[mi][ni][rg] + bf2f(xt[lrow * XLD + cols[ni]]) + bcol[ni];
          acc[mi][ni][rg] = t2;
          a += t2; b += t2 * t2;
        }
        a += __shfl_xor(a, 8); b += __shfl_xor(b, 8);
        a += __shfl_xor(a, 4); b += __shfl_xor(b, 4);
        if ((fr & 12) == 0) sh.ln.part[lrow][wave * 4 + fr] = float2{a, b};
      }
    __syncthreads();
    if (tid < 32) {
      float s = 0.f, s2 = 0.f;
      #pragma unroll
      for (int f = 0; f < 16; f += 2) {
        float4 p = *(const float4*)&sh.ln.part[tid][f];
        s += p.x + p.z; s2 += p.y + p.w;
      }
      float mean = s * (1.f / 256.f);
      float var = fmaxf(s2 * (1.f / 256.f) - mean * mean, 0.f);
      sh.ln.ms[tid] = float2{mean, rsqrtf(var + 1e-5f)};
    }
    __syncthreads();
    float gcol[4], btc[4];
    #pragma unroll
    for (int ni = 0; ni < 4; ++ni) { gcol[ni] = bf2f(gamma[cols[ni]]); btc[ni] = bf2f(beta[cols[ni]]); }
    #pragma unroll
    for (int mi = 0; mi < 2; ++mi)
      #pragma unroll
      for (int rg = 0; rg < 4; ++rg) {
        int lrow = mi * 16 + fq * 4 + rg;
        float2 ms = sh.ln.ms[lrow];
        #pragma unroll
        for (int ni = 0; ni < 4; ++ni) {
          float o = (acc[mi][ni][rg] - ms.x) * ms.y * gcol[ni] + btc[ni];
          xt[lrow * XLD + cols[ni]] = f2bf(o);
        }
      }
    __syncthreads();
  };

  for (int l = 0; l < 2; ++l) {
    // ---------- attn: acc = cos(xt + theta) @ cwT, BK=32 (8 iters) ----------
    #pragma unroll
    for (int i = 0; i < 2; ++i)
      #pragma unroll
      for (int j = 0; j < 4; ++j) acc[i][j] = {0.f, 0.f, 0.f, 0.f};
    {
      const u16* Bbase = cwT + l * 65536;
      const u16* th = canon + l * 64;
      for (int k0 = 0; k0 < 256; k0 += 32) {
        const u16* bsrc = Bbase + (k0 >> 3) * 2048;
        #pragma unroll
        for (int it = 0; it < 4; ++it) {
          int c = tid + it * 256;
          __builtin_amdgcn_global_load_lds(
              (const __attribute__((address_space(1))) void*)(bsrc + (size_t)c * 8),
              (__attribute__((address_space(3))) void*)(sh.k.Bt + c * 8), 16, 0, 0);
        }
        // A: 32x32 tile; thread = (row sr_, 4 cols at k0+sg*4)
        {
          int kc = sg >> 1, sub = (sg & 1) * 4;
          uint2 g = *(const uint2*)(xt + sr_ * XLD + k0 + sg * 4);
          uint2 t = *(const uint2*)(th + ((k0 + sg * 4) & 63));
          u16* gp = (u16*)&g; const u16* tp = (const u16*)&t;
          #pragma unroll
          for (int j = 0; j < 4; ++j)
            gp[j] = f2bf(fast_cos(bf2f(gp[j]) + bf2f(tp[j])));
          *(uint2*)(sh.k.At + (kc * 32 + (sr_ ^ kc)) * 8 + sub) = g;
        }
        __syncthreads();
        mfma_step();
        __syncthreads();
      }
    }
    epilogue(canon + 131200 + l * 256, canon + 403600 + l * 256, canon + 404112 + l * 256);

    // ---------- q = cos(xt[:, :8]) * cos(ffn_theta) -> REGISTERS ----------
    float qv[8];
    {
      uint4 xv = *(const uint4*)(xt + sr_ * XLD);
      uint4 tv = *(const uint4*)(canon + 131712 + l * 8);
      const u16* xp = (const u16*)&xv; const u16* tp = (const u16*)&tv;
      #pragma unroll
      for (int j = 0; j < 8; ++j)
        qv[j] = fast_cos(bf2f(xp[j])) * fast_cos(bf2f(tp[j]));
    }

    // ---------- ffn: h = relu(q @ W1 + b1) (VALU, f32 wts); acc += h @ l2T (16 iters) ----------
    #pragma unroll
    for (int i = 0; i < 2; ++i)
      #pragma unroll
      for (int j = 0; j < 4; ++j) acc[i][j] = {0.f, 0.f, 0.f, 0.f};
    {
      const u16* B2 = l2T + l * 131072;
      const float* w1l = w1f + l * 4096;
      const float* b1l = b1f + l * 512;
      for (int k0 = 0; k0 < 512; k0 += 32) {
        const u16* bsrc = B2 + (k0 >> 3) * 2048;
        #pragma unroll
        for (int it = 0; it < 4; ++it) {
          int c = tid + it * 256;
          __builtin_amdgcn_global_load_lds(
              (const __attribute__((address_space(1))) void*)(bsrc + (size_t)c * 8),
              (__attribute__((address_space(3))) void*)(sh.k.Bt + c * 8), 16, 0, 0);
        }
        // h: thread = (row sr_, 4 cols at k0+sg*4); q from registers
        {
          int kc = sg >> 1, sub = (sg & 1) * 4;
          float4 hv4 = *(const float4*)(b1l + k0 + sg * 4);
          float hv[4] = {hv4.x, hv4.y, hv4.z, hv4.w};
          #pragma unroll
          for (int n = 0; n < 8; ++n) {
            float4 w = *(const float4*)(w1l + n * 512 + k0 + sg * 4);  // near-uniform, L1-hot
            hv[0] += qv[n] * w.x; hv[1] += qv[n] * w.y;
            hv[2] += qv[n] * w.z; hv[3] += qv[n] * w.w;
          }
          uint2 g; u16* gp = (u16*)&g;
          #pragma unroll
          for (int j = 0; j < 4; ++j) gp[j] = f2bf(fmaxf(hv[j], 0.f));
          *(uint2*)(sh.k.At + (kc * 32 + (sr_ ^ kc)) * 8 + sub) = g;
        }
        __syncthreads();
        mfma_step();
        __syncthreads();
      }
    }
    epilogue(canon + 403088 + l * 256, canon + 404624 + l * 256, canon + 405136 + l * 256);
  }

  // ---------- pool: column sums of the 32-row tile ----------
  {
    float s = 0.f;
    #pragma unroll 8
    for (int r = 0; r < 32; ++r) s += bf2f(xt[r * XLD + tid]);
    atomicAdd(&pooled[(m0 >> 11) * EDIM + tid], s);
  }
}

__global__ void logits_kernel(const float* __restrict__ pooled, const u16* __restrict__ clsw,
                              const u16* __restrict__ clsb, const void* __restrict__ embed,
                              void* __restrict__ out) {
  const int isf32 = sniff128(embed);
  int t = threadIdx.x;
  int b = t >> 4, sub = t & 15;
  float a0 = 0.f, a1 = 0.f;
  #pragma unroll
  for (int j = 0; j < 16; ++j) {
    int e = sub * 16 + j;
    float p = pooled[b * 256 + e];
    a0 += p * bf2f(clsw[e * 2 + 0]);
    a1 += p * bf2f(clsw[e * 2 + 1]);
  }
  #pragma unroll
  for (int d = 1; d < 16; d <<= 1) {
    a0 += __shfl_xor(a0, d);
    a1 += __shfl_xor(a1, d);
  }
  if (sub == 0) {
    float o0 = a0 * (1.f / 2048.f) + bf2f(clsb[0]);
    float o1 = a1 * (1.f / 2048.f) + bf2f(clsb[1]);
    if (isf32) {
      ((float*)out)[b * 2 + 0] = o0; ((float*)out)[b * 2 + 1] = o1;
    } else {
      ((u16*)out)[b * 2 + 0] = f2bf(o0); ((u16*)out)[b * 2 + 1] = f2bf(o1);
    }
  }
}

extern "C" void kernel_launch(void* const* d_in, const int* in_sizes, int n_in,
                              void* d_out, int out_size, void* d_ws, size_t ws_size,
                              hipStream_t stream) {
  const int* tokens = (const int*)d_in[0];

  char* ws = (char*)d_ws;
  u16*   canon  = (u16*)(ws + 0);              // 812 KB bf16 params
  u16*   cwT    = (u16*)(ws + 1048576);        // 256 KB [2][K/8][256][8]
  u16*   l2T    = (u16*)(ws + 1310720);        // 512 KB
  float* w1f    = (float*)(ws + 1835008);      //  32 KB [2][8][512] f32
  float* b1f    = (float*)(ws + 1867776);      //   4 KB [2][512] f32
  float* pooled = (float*)(ws + 1871872);      //  16 KB

  CanonArgs ca;
  for (int i = 0; i < 14; ++i) ca.p[i] = d_in[i + 2];

  prep_kernel<<<3159, 256, 0, stream>>>(d_in[1], ca, canon, cwT, l2T, w1f, b1f);
  hipMemsetAsync(pooled, 0, NBATCH * EDIM * sizeof(float), stream);

  mega_kernel<<<1024, 256, 0, stream>>>(tokens, d_in[1], canon, cwT, l2T, w1f, b1f, pooled);

  logits_kernel<<<1, 256, 0, stream>>>(pooled, canon + 405648, canon + 406160, d_in[1], d_out);
}